// Round 9
// baseline (54.338 us; speedup 1.0000x reference)
//
#include <hip/hip_runtime.h>

typedef float v2f __attribute__((ext_vector_type(2)));

// compile-time DPP move: dest lane gets src lane per CTRL pattern.
// NOTE: must be executed with the source lanes ACTIVE — DPP reads from an
// EXEC-disabled lane return 0 (bound_ctrl). Always hoist above divergence.
template<int CTRL>
__device__ __forceinline__ float dppmov(float x) {
    return __builtin_bit_cast(float,
        __builtin_amdgcn_update_dpp(0, __builtin_bit_cast(int, x),
                                    CTRL, 0xf, 0xf, true));
}
#define DPP_XOR1  0xB1   // quad_perm [1,0,3,2]
#define DPP_XOR2  0x4E   // quad_perm [2,3,0,1]
#define DPP_XOR8  0x128  // row_ror:8 == lane^8 within 16-lane rows
#define DPP_SHR(d) (0x110 | (d))

// packed penetration: row sphere rs vs column spheres of links (j1,j2)
// packed in v2f {j1,j2}. m[i] folds with v_max3; m[j1], m[j2] plain max.
__device__ __forceinline__ void pen2j(const float4& rs,
                                      v2f cx, v2f cy, v2f cz, v2f cw,
                                      float& mi, float& mj1, float& mj2)
{
    v2f dx = cx - rs.x;
    v2f dy = cy - rs.y;
    v2f dz = cz - rs.z;
    v2f d2 = dx * dx;
    d2 = __builtin_elementwise_fma(dy, dy, d2);
    d2 = __builtin_elementwise_fma(dz, dz, d2);
    v2f pen = (cw + rs.w) - (v2f){__builtin_amdgcn_sqrtf(d2.x),
                                  __builtin_amdgcn_sqrtf(d2.y)};
    mi  = fmaxf(fmaxf(mi, pen.x), pen.y);   // v_max3_f32
    mj1 = fmaxf(mj1, pen.x);
    mj2 = fmaxf(mj2, pen.y);
}

__device__ __forceinline__ void pen1s(const float4& rs,
                                      float cx, float cy, float cz, float cw,
                                      float& mi, float& mj)
{
    float dx = cx - rs.x, dy = cy - rs.y, dz = cz - rs.z;
    float d2 = fmaf(dx, dx, fmaf(dy, dy, dz * dz));
    float p  = cw + rs.w - __builtin_amdgcn_sqrtf(d2);
    mi = fmaxf(mi, p);
    mj = fmaxf(mj, p);
}

// ---------------------------------------------------------------------------
// ONE batch per wave, body engineered for <=64 VGPR -> 8 waves/SIMD.
// (R8 failed from DPP-under-divergence on the translation reads — fixed:
//  ALL dpp reads hoisted above the `if (l >= D)` divergence.)
//  - FK prefix product via DPP row_shr; R overwritten column-by-column.
//  - Spheres in padded LDS (stride 9 float4), wave-private slice, no barrier.
//  - Pair loop: columns packed across ADJACENT links (j,j+1) as v2f (born
//    packed via paired LDS reads 36 dwords apart); two 7-column passes.
//  - Per-link wave max: log-fold, 13 DPP + 3 shfl.
// ---------------------------------------------------------------------------
__global__ __launch_bounds__(256, 8) void fused_kernel(
    const float* __restrict__ q,        // [B,16]
    const float* __restrict__ frot,     // [16,3,3]
    const float* __restrict__ ftrans,   // [16,3]
    const float* __restrict__ axes,     // [16,3]
    const float* __restrict__ spheres,  // [16,8,4]
    float* __restrict__ out,            // [B,16]
    int B)
{
    __shared__ float4 sph[4][16 * 9];
    const int t    = threadIdx.x;
    const int w    = t >> 6;
    const int lane = t & 63;
    int b = blockIdx.x * 4 + w;
    const bool alive = (b < B);
    if (!alive) b = B - 1;

    const int l = lane & 15;            // link this lane owns in FK phase
    const int g = lane >> 4;            // sphere-group (2 spheres each)

    const float qv = q[(size_t)b * 16 + l];
    const float s = __sinf(qv), c = __cosf(qv), oc = 1.0f - c;
    const float ax = axes[3*l+0], ay = axes[3*l+1], az = axes[3*l+2];

    // ---- local joint transform R = F * J(axis,q), row-wise (F rows die fast)
    float R00,R01,R02,R10,R11,R12,R20,R21,R22;
    #define BUILD_ROW(Ra, Rb, Rc, base)                                         \
    {                                                                           \
        float f0 = frot[base+0], f1 = frot[base+1], f2 = frot[base+2];          \
        float u0 = fmaf(f1,az, -f2*ay);                                         \
        float u1 = fmaf(f2,ax, -f0*az);                                         \
        float u2 = fmaf(f0,ay, -f1*ax);                                         \
        float v0 = fmaf(u1,az, -u2*ay);                                         \
        float v1 = fmaf(u2,ax, -u0*az);                                         \
        float v2 = fmaf(u0,ay, -u1*ax);                                         \
        Ra = fmaf(oc,v0, fmaf(s,u0, f0));                                       \
        Rb = fmaf(oc,v1, fmaf(s,u1, f1));                                       \
        Rc = fmaf(oc,v2, fmaf(s,u2, f2));                                       \
    }
    BUILD_ROW(R00,R01,R02, 9*l+0)
    BUILD_ROW(R10,R11,R12, 9*l+3)
    BUILD_ROW(R20,R21,R22, 9*l+6)
    #undef BUILD_ROW
    float t0 = ftrans[3*l+0], t1 = ftrans[3*l+1], t2 = ftrans[3*l+2];

    // ---- Kogge-Stone prefix product; ALL dpp reads hoisted above divergence
    #define SCAN_STEP(D, CTRL)                                                  \
    {                                                                           \
        float P00 = dppmov<CTRL>(R00), P01 = dppmov<CTRL>(R01), P02 = dppmov<CTRL>(R02); \
        float P10 = dppmov<CTRL>(R10), P11 = dppmov<CTRL>(R11), P12 = dppmov<CTRL>(R12); \
        float P20 = dppmov<CTRL>(R20), P21 = dppmov<CTRL>(R21), P22 = dppmov<CTRL>(R22); \
        float pt0 = dppmov<CTRL>(t0),  pt1 = dppmov<CTRL>(t1),  pt2 = dppmov<CTRL>(t2);  \
        if (l >= (D)) {                                                         \
            {   float n0 = fmaf(P00,t0, fmaf(P01,t1, fmaf(P02,t2, pt0)));       \
                float n1 = fmaf(P10,t0, fmaf(P11,t1, fmaf(P12,t2, pt1)));       \
                float n2 = fmaf(P20,t0, fmaf(P21,t1, fmaf(P22,t2, pt2)));       \
                t0 = n0; t1 = n1; t2 = n2;                                      \
            }                                                                   \
            {   float a = fmaf(P00,R00, fmaf(P01,R10, P02*R20));                \
                float d = fmaf(P10,R00, fmaf(P11,R10, P12*R20));                \
                float e = fmaf(P20,R00, fmaf(P21,R10, P22*R20));                \
                R00 = a; R10 = d; R20 = e; }                                    \
            {   float a = fmaf(P00,R01, fmaf(P01,R11, P02*R21));                \
                float d = fmaf(P10,R01, fmaf(P11,R11, P12*R21));                \
                float e = fmaf(P20,R01, fmaf(P21,R11, P22*R21));                \
                R01 = a; R11 = d; R21 = e; }                                    \
            {   float a = fmaf(P00,R02, fmaf(P01,R12, P02*R22));                \
                float d = fmaf(P10,R02, fmaf(P11,R12, P12*R22));                \
                float e = fmaf(P20,R02, fmaf(P21,R12, P22*R22));                \
                R02 = a; R12 = d; R22 = e; }                                    \
        }                                                                       \
    }
    SCAN_STEP(1, DPP_SHR(1))
    SCAN_STEP(2, DPP_SHR(2))
    SCAN_STEP(4, DPP_SHR(4))
    SCAN_STEP(8, DPP_SHR(8))
    #undef SCAN_STEP

    // ---- transform this lane's 2 spheres of link l into padded LDS
    #pragma unroll
    for (int k = 0; k < 2; ++k) {
        const int sp = g * 2 + k;
        float4 cs = reinterpret_cast<const float4*>(spheres)[l*8 + sp];
        float wx = fmaf(R00,cs.x, fmaf(R01,cs.y, fmaf(R02,cs.z, t0)));
        float wy = fmaf(R10,cs.x, fmaf(R11,cs.y, fmaf(R12,cs.z, t1)));
        float wz = fmaf(R20,cs.x, fmaf(R21,cs.y, fmaf(R22,cs.z, t2)));
        sph[w][l*9 + sp] = make_float4(wx, wy, wz, cs.w);
    }
    asm volatile("s_waitcnt lgkmcnt(0)" ::: "memory");

    // ---- pairwise penetration (64 lanes on one batch)
    const float4* S  = sph[w];
    const float*  Sf = reinterpret_cast<const float*>(S);
    const int sr = lane >> 3;      // row sphere 0..7
    const int sc = lane & 7;       // col sphere 0..7

    float m[16];
    #pragma unroll
    for (int k = 0; k < 16; ++k) m[k] = -100.0f;

    // born-packed fill across links (j, j+1): paired reads 36 dwords apart
    #define FILL_P(idx, j)                                                      \
    {                                                                           \
        const int bd = (j)*36 + sc*4;                                           \
        px[idx] = (v2f){Sf[bd+0], Sf[bd+36]};                                   \
        py[idx] = (v2f){Sf[bd+1], Sf[bd+37]};                                   \
        pz[idx] = (v2f){Sf[bd+2], Sf[bd+38]};                                   \
        pw[idx] = (v2f){Sf[bd+3], Sf[bd+39]};                                   \
    }

    // ---- Pass A: columns j in [2,8]  (pairs (2,3),(4,5),(6,7) + single 8)
    {
        v2f px[3], py[3], pz[3], pw[3];
        FILL_P(0, 2) FILL_P(1, 4) FILL_P(2, 6)
        float4 s8 = S[8*9 + sc];

        float4 rs = S[0*9 + sr];
        pen2j(rs, px[0],py[0],pz[0],pw[0], m[0], m[2], m[3]);
        pen2j(rs, px[1],py[1],pz[1],pw[1], m[0], m[4], m[5]);
        pen2j(rs, px[2],py[2],pz[2],pw[2], m[0], m[6], m[7]);
        pen1s(rs, s8.x,s8.y,s8.z,s8.w, m[0], m[8]);

        rs = S[1*9 + sr];
        pen1s(rs, px[0].y,py[0].y,pz[0].y,pw[0].y, m[1], m[3]);
        pen2j(rs, px[1],py[1],pz[1],pw[1], m[1], m[4], m[5]);
        pen2j(rs, px[2],py[2],pz[2],pw[2], m[1], m[6], m[7]);
        pen1s(rs, s8.x,s8.y,s8.z,s8.w, m[1], m[8]);

        rs = S[2*9 + sr];
        pen2j(rs, px[1],py[1],pz[1],pw[1], m[2], m[4], m[5]);
        pen2j(rs, px[2],py[2],pz[2],pw[2], m[2], m[6], m[7]);
        pen1s(rs, s8.x,s8.y,s8.z,s8.w, m[2], m[8]);

        rs = S[3*9 + sr];
        pen1s(rs, px[1].y,py[1].y,pz[1].y,pw[1].y, m[3], m[5]);
        pen2j(rs, px[2],py[2],pz[2],pw[2], m[3], m[6], m[7]);
        pen1s(rs, s8.x,s8.y,s8.z,s8.w, m[3], m[8]);

        rs = S[4*9 + sr];
        pen2j(rs, px[2],py[2],pz[2],pw[2], m[4], m[6], m[7]);
        pen1s(rs, s8.x,s8.y,s8.z,s8.w, m[4], m[8]);

        rs = S[5*9 + sr];
        pen1s(rs, px[2].y,py[2].y,pz[2].y,pw[2].y, m[5], m[7]);
        pen1s(rs, s8.x,s8.y,s8.z,s8.w, m[5], m[8]);

        rs = S[6*9 + sr];
        pen1s(rs, s8.x,s8.y,s8.z,s8.w, m[6], m[8]);
    }

    // ---- Pass B: columns j in [9,15] (pairs (9,10),(11,12),(13,14) + single 15)
    {
        v2f px[3], py[3], pz[3], pw[3];
        FILL_P(0, 9) FILL_P(1, 11) FILL_P(2, 13)
        float4 s15 = S[15*9 + sc];

        #pragma unroll
        for (int i = 0; i <= 7; ++i) {
            float4 rs = S[i*9 + sr];
            pen2j(rs, px[0],py[0],pz[0],pw[0], m[i], m[9],  m[10]);
            pen2j(rs, px[1],py[1],pz[1],pw[1], m[i], m[11], m[12]);
            pen2j(rs, px[2],py[2],pz[2],pw[2], m[i], m[13], m[14]);
            pen1s(rs, s15.x,s15.y,s15.z,s15.w, m[i], m[15]);
        }

        float4 rs = S[8*9 + sr];
        pen1s(rs, px[0].y,py[0].y,pz[0].y,pw[0].y, m[8], m[10]);
        pen2j(rs, px[1],py[1],pz[1],pw[1], m[8], m[11], m[12]);
        pen2j(rs, px[2],py[2],pz[2],pw[2], m[8], m[13], m[14]);
        pen1s(rs, s15.x,s15.y,s15.z,s15.w, m[8], m[15]);

        rs = S[9*9 + sr];
        pen2j(rs, px[1],py[1],pz[1],pw[1], m[9], m[11], m[12]);
        pen2j(rs, px[2],py[2],pz[2],pw[2], m[9], m[13], m[14]);
        pen1s(rs, s15.x,s15.y,s15.z,s15.w, m[9], m[15]);

        rs = S[10*9 + sr];
        pen1s(rs, px[1].y,py[1].y,pz[1].y,pw[1].y, m[10], m[12]);
        pen2j(rs, px[2],py[2],pz[2],pw[2], m[10], m[13], m[14]);
        pen1s(rs, s15.x,s15.y,s15.z,s15.w, m[10], m[15]);

        rs = S[11*9 + sr];
        pen2j(rs, px[2],py[2],pz[2],pw[2], m[11], m[13], m[14]);
        pen1s(rs, s15.x,s15.y,s15.z,s15.w, m[11], m[15]);

        rs = S[12*9 + sr];
        pen1s(rs, px[2].y,py[2].y,pz[2].y,pw[2].y, m[12], m[14]);
        pen1s(rs, s15.x,s15.y,s15.z,s15.w, m[12], m[15]);

        rs = S[13*9 + sr];
        pen1s(rs, s15.x,s15.y,s15.z,s15.w, m[13], m[15]);
    }
    #undef FILL_P

    // ---- log-fold wave reduction (13 DPP + 3 shfl)
    {
        int bit0 = lane & 1;
        #pragma unroll
        for (int k = 0; k < 8; ++k) {
            float send = bit0 ? m[k] : m[k+8];
            float recv = dppmov<DPP_XOR1>(send);
            m[k] = fmaxf(bit0 ? m[k+8] : m[k], recv);
        }
        int bit1 = (lane >> 1) & 1;
        #pragma unroll
        for (int k = 0; k < 4; ++k) {
            float send = bit1 ? m[k] : m[k+4];
            float recv = dppmov<DPP_XOR2>(send);
            m[k] = fmaxf(bit1 ? m[k+4] : m[k], recv);
        }
        int bit2 = (lane >> 2) & 1;
        #pragma unroll
        for (int k = 0; k < 2; ++k) {
            float send = bit2 ? m[k] : m[k+2];
            float recv = __shfl_xor(send, 4, 64);
            m[k] = fmaxf(bit2 ? m[k+2] : m[k], recv);
        }
        int bit3 = (lane >> 3) & 1;
        {
            float send = bit3 ? m[0] : m[1];
            float recv = dppmov<DPP_XOR8>(send);
            m[0] = fmaxf(bit3 ? m[1] : m[0], recv);
        }
        float v = m[0];
        v = fmaxf(v, __shfl_xor(v, 16, 64));
        v = fmaxf(v, __shfl_xor(v, 32, 64));
        m[0] = v;
    }

    if (alive && lane < 16) {
        int k = ((lane & 1) << 3) | ((lane & 2) << 1) | ((lane & 4) >> 1) | ((lane & 8) >> 3);
        out[(size_t)b * 16 + k] = m[0];
    }
}

// ---------------------------------------------------------------------------
extern "C" void kernel_launch(void* const* d_in, const int* in_sizes, int n_in,
                              void* d_out, int out_size, void* d_ws, size_t ws_size,
                              hipStream_t stream) {
    const float* q      = (const float*)d_in[0];
    const float* frot   = (const float*)d_in[1];
    const float* ftrans = (const float*)d_in[2];
    const float* axes   = (const float*)d_in[3];
    const float* sphere = (const float*)d_in[4];
    float* out = (float*)d_out;

    const int B = in_sizes[0] / 16;
    const int blocks = (B + 3) / 4;     // 1 batch per wave, 4 per block
    fused_kernel<<<dim3(blocks), dim3(256), 0, stream>>>(
        q, frot, ftrans, axes, sphere, out, B);
}

// Round 10
// 19.997 us; speedup vs baseline: 2.7173x; 2.7173x over previous
//
#include <hip/hip_runtime.h>

typedef float v2f __attribute__((ext_vector_type(2)));

// compile-time DPP move: dest lane gets src lane per CTRL pattern.
// bound_ctrl=true: lanes whose source falls outside the 16-lane row read 0.
// NOTE: execute with source lanes ACTIVE (EXEC-disabled sources read 0).
template<int CTRL>
__device__ __forceinline__ float dppmov(float x) {
    return __builtin_bit_cast(float,
        __builtin_amdgcn_update_dpp(0, __builtin_bit_cast(int, x),
                                    CTRL, 0xf, 0xf, true));
}
#define DPP_XOR1  0xB1   // quad_perm [1,0,3,2]
#define DPP_XOR2  0x4E   // quad_perm [2,3,0,1]
#define DPP_XOR8  0x128  // row_ror:8 == lane^8 within 16-lane rows
#define DPP_SHR(d) (0x110 | (d))

// packed penetration: one row sphere vs packed column spheres {sc2, sc2+4}
// of the SAME link j -> both maxes fold with v_max3.
__device__ __forceinline__ void pen2p(const float4& rs,
                                      v2f cx, v2f cy, v2f cz, v2f cw,
                                      float& mi, float& mj)
{
    v2f dx = cx - rs.x;
    v2f dy = cy - rs.y;
    v2f dz = cz - rs.z;
    v2f d2 = dx * dx;
    d2 = __builtin_elementwise_fma(dy, dy, d2);
    d2 = __builtin_elementwise_fma(dz, dz, d2);
    v2f pen = (cw + rs.w) - (v2f){__builtin_amdgcn_sqrtf(d2.x),
                                  __builtin_amdgcn_sqrtf(d2.y)};
    mi = fmaxf(fmaxf(mi, pen.x), pen.y);   // v_max3_f32
    mj = fmaxf(fmaxf(mj, pen.x), pen.y);   // v_max3_f32
}

// ---------------------------------------------------------------------------
// Fully fused, TWO batches per wave (lanes 0-31 batch A, 32-63 batch B).
// 128-reg tier (launch_bounds (256,4)) — the <=64-reg tier is unreachable
// without catastrophic spills (R6/R9: 150+ MB scratch traffic).
//  - FK prefix product via DPP row_shr, BRANCHLESS: bound_ctrl zeros P/pt for
//    lanes l<D; 3 cndmasks force P diag to 1 -> those lanes compute N=I*R=R,
//    t=I*t+0=t exactly. No divergent exec-mask regions in the scan.
//  - Each lane transforms 4 spheres of its link into padded LDS (stride 9).
//  - Pair phase: 32 lanes per batch; lane owns (row sr = L>>2, cols {sc2,sc2+4});
//    column cache born-packed as v2f via paired LDS scalar loads (ds_read2).
//  - Per-link max: log-fold, 13 DPP + 2 shfl + xor16 merge.
// ---------------------------------------------------------------------------
__global__ __launch_bounds__(256, 4) void fused_kernel(
    const float* __restrict__ q,        // [B,16]
    const float* __restrict__ frot,     // [16,3,3]
    const float* __restrict__ ftrans,   // [16,3]
    const float* __restrict__ axes,     // [16,3]
    const float* __restrict__ spheres,  // [16,8,4]
    float* __restrict__ out,            // [B,16]
    int B)
{
    __shared__ float4 sph[4][2][16 * 9];   // [wave][batch-half][link*9 + sphere]
    const int t    = threadIdx.x;
    const int w    = t >> 6;
    const int lane = t & 63;
    const int h    = lane >> 5;            // batch half within wave
    int b = blockIdx.x * 8 + w * 2 + h;
    const bool alive = (b < B);
    if (!alive) b = B - 1;

    const int l = lane & 15;               // link this lane owns in FK phase
    const int g = (lane >> 4) & 1;         // sphere-group (4 spheres each)

    // ---- local joint transform: R = F * J(axis,q)
    const float qv = q[(size_t)b * 16 + l];
    const float s = __sinf(qv), c = __cosf(qv), oc = 1.0f - c;
    const float ax = axes[3*l+0], ay = axes[3*l+1], az = axes[3*l+2];

    const float F00=frot[9*l+0], F01=frot[9*l+1], F02=frot[9*l+2];
    const float F10=frot[9*l+3], F11=frot[9*l+4], F12=frot[9*l+5];
    const float F20=frot[9*l+6], F21=frot[9*l+7], F22=frot[9*l+8];

    float R00,R01,R02,R10,R11,R12,R20,R21,R22;
    {
        float u0 = fmaf(F01,az, -F02*ay);
        float u1 = fmaf(F02,ax, -F00*az);
        float u2 = fmaf(F00,ay, -F01*ax);
        float v0 = fmaf(u1,az, -u2*ay);
        float v1 = fmaf(u2,ax, -u0*az);
        float v2 = fmaf(u0,ay, -u1*ax);
        R00 = fmaf(oc,v0, fmaf(s,u0, F00));
        R01 = fmaf(oc,v1, fmaf(s,u1, F01));
        R02 = fmaf(oc,v2, fmaf(s,u2, F02));

        u0 = fmaf(F11,az, -F12*ay);
        u1 = fmaf(F12,ax, -F10*az);
        u2 = fmaf(F10,ay, -F11*ax);
        v0 = fmaf(u1,az, -u2*ay);
        v1 = fmaf(u2,ax, -u0*az);
        v2 = fmaf(u0,ay, -u1*ax);
        R10 = fmaf(oc,v0, fmaf(s,u0, F10));
        R11 = fmaf(oc,v1, fmaf(s,u1, F11));
        R12 = fmaf(oc,v2, fmaf(s,u2, F12));

        u0 = fmaf(F21,az, -F22*ay);
        u1 = fmaf(F22,ax, -F20*az);
        u2 = fmaf(F20,ay, -F21*ax);
        v0 = fmaf(u1,az, -u2*ay);
        v1 = fmaf(u2,ax, -u0*az);
        v2 = fmaf(u0,ay, -u1*ax);
        R20 = fmaf(oc,v0, fmaf(s,u0, F20));
        R21 = fmaf(oc,v1, fmaf(s,u1, F21));
        R22 = fmaf(oc,v2, fmaf(s,u2, F22));
    }
    float t0 = ftrans[3*l+0], t1 = ftrans[3*l+1], t2 = ftrans[3*l+2];

    // ---- branchless Kogge-Stone prefix product over width-16 segments
    #define SCAN_STEP(D, CTRL)                                                  \
    {                                                                           \
        float P00 = dppmov<CTRL>(R00), P01 = dppmov<CTRL>(R01), P02 = dppmov<CTRL>(R02); \
        float P10 = dppmov<CTRL>(R10), P11 = dppmov<CTRL>(R11), P12 = dppmov<CTRL>(R12); \
        float P20 = dppmov<CTRL>(R20), P21 = dppmov<CTRL>(R21), P22 = dppmov<CTRL>(R22); \
        float pt0 = dppmov<CTRL>(t0),  pt1 = dppmov<CTRL>(t1),  pt2 = dppmov<CTRL>(t2);  \
        const bool lo = (l < (D));      /* P,pt are 0 here (bound_ctrl) */      \
        P00 = lo ? 1.0f : P00;                                                  \
        P11 = lo ? 1.0f : P11;                                                  \
        P22 = lo ? 1.0f : P22;          /* P = I for lo lanes -> exact no-op */ \
        {                                                                       \
            float n00 = fmaf(P00,R00, fmaf(P01,R10, P02*R20));                  \
            float n01 = fmaf(P00,R01, fmaf(P01,R11, P02*R21));                  \
            float n02 = fmaf(P00,R02, fmaf(P01,R12, P02*R22));                  \
            float n10 = fmaf(P10,R00, fmaf(P11,R10, P12*R20));                  \
            float n11 = fmaf(P10,R01, fmaf(P11,R11, P12*R21));                  \
            float n12 = fmaf(P10,R02, fmaf(P11,R12, P12*R22));                  \
            float n20 = fmaf(P20,R00, fmaf(P21,R10, P22*R20));                  \
            float n21 = fmaf(P20,R01, fmaf(P21,R11, P22*R21));                  \
            float n22 = fmaf(P20,R02, fmaf(P21,R12, P22*R22));                  \
            float nt0 = fmaf(P00,t0, fmaf(P01,t1, fmaf(P02,t2, pt0)));          \
            float nt1 = fmaf(P10,t0, fmaf(P11,t1, fmaf(P12,t2, pt1)));          \
            float nt2 = fmaf(P20,t0, fmaf(P21,t1, fmaf(P22,t2, pt2)));          \
            R00=n00; R01=n01; R02=n02;                                          \
            R10=n10; R11=n11; R12=n12;                                          \
            R20=n20; R21=n21; R22=n22;                                          \
            t0=nt0; t1=nt1; t2=nt2;                                             \
        }                                                                       \
    }
    SCAN_STEP(1, DPP_SHR(1))
    SCAN_STEP(2, DPP_SHR(2))
    SCAN_STEP(4, DPP_SHR(4))
    SCAN_STEP(8, DPP_SHR(8))
    #undef SCAN_STEP

    // ---- transform this lane's 4 spheres of link l into padded LDS
    #pragma unroll
    for (int k = 0; k < 4; ++k) {
        const int sp = g * 4 + k;
        float4 cs = reinterpret_cast<const float4*>(spheres)[l*8 + sp];
        float wx = fmaf(R00,cs.x, fmaf(R01,cs.y, fmaf(R02,cs.z, t0)));
        float wy = fmaf(R10,cs.x, fmaf(R11,cs.y, fmaf(R12,cs.z, t1)));
        float wz = fmaf(R20,cs.x, fmaf(R21,cs.y, fmaf(R22,cs.z, t2)));
        sph[w][h][l*9 + sp] = make_float4(wx, wy, wz, cs.w);
    }
    // wave-private LDS region: just drain this wave's writes, no barrier
    asm volatile("s_waitcnt lgkmcnt(0)" ::: "memory");

    // ---- pairwise penetration, per-link max (32 lanes per batch)
    const float4* S  = sph[w][h];
    const float*  Sf = reinterpret_cast<const float*>(S);
    const int L   = lane & 31;
    const int sr  = L >> 2;        // row sphere 0..7
    const int sc2 = L & 3;         // column spheres {sc2, sc2+4}

    float m[16];
    #pragma unroll
    for (int k = 0; k < 16; ++k) m[k] = -100.0f;

    // column cache fill: paired scalar LDS loads (-> ds_read2_b32), born packed
    #define FILL_CS(jj, j)                                                      \
    {                                                                           \
        const int bd = (j)*36 + sc2*4;                                          \
        cx[jj] = (v2f){Sf[bd+0], Sf[bd+16]};                                    \
        cy[jj] = (v2f){Sf[bd+1], Sf[bd+17]};                                    \
        cz[jj] = (v2f){Sf[bd+2], Sf[bd+18]};                                    \
        cw[jj] = (v2f){Sf[bd+3], Sf[bd+19]};                                    \
    }

    // ---- Pass A: columns j in [2,8], rows i in [0,6]
    {
        v2f cx[7], cy[7], cz[7], cw[7];
        #pragma unroll
        for (int j = 2; j <= 8; ++j) FILL_CS(j-2, j)

        #pragma unroll
        for (int i = 0; i <= 6; ++i) {
            float4 rs = S[i*9 + sr];
            #pragma unroll
            for (int j = i + 2; j <= 8; ++j)
                pen2p(rs, cx[j-2], cy[j-2], cz[j-2], cw[j-2], m[i], m[j]);
        }
    }
    // ---- Pass B: columns j in [9,15], rows i in [0,13]
    {
        v2f cx[7], cy[7], cz[7], cw[7];
        #pragma unroll
        for (int j = 9; j <= 15; ++j) FILL_CS(j-9, j)

        #pragma unroll
        for (int i = 0; i <= 13; ++i) {
            float4 rs = S[i*9 + sr];
            const int j0 = (i + 2 > 9) ? (i + 2) : 9;
            #pragma unroll
            for (int j = 9; j <= 15; ++j) {
                if (j < j0) continue;
                pen2p(rs, cx[j-9], cy[j-9], cz[j-9], cw[j-9], m[i], m[j]);
            }
        }
    }
    #undef FILL_CS

    // ---- log-fold reduction over the 32 lanes of this batch half
    {
        int bit0 = lane & 1;
        #pragma unroll
        for (int k = 0; k < 8; ++k) {
            float send = bit0 ? m[k] : m[k+8];
            float recv = dppmov<DPP_XOR1>(send);
            m[k] = fmaxf(bit0 ? m[k+8] : m[k], recv);
        }
        int bit1 = (lane >> 1) & 1;
        #pragma unroll
        for (int k = 0; k < 4; ++k) {
            float send = bit1 ? m[k] : m[k+4];
            float recv = dppmov<DPP_XOR2>(send);
            m[k] = fmaxf(bit1 ? m[k+4] : m[k], recv);
        }
        int bit2 = (lane >> 2) & 1;
        #pragma unroll
        for (int k = 0; k < 2; ++k) {
            float send = bit2 ? m[k] : m[k+2];
            float recv = __shfl_xor(send, 4, 64);
            m[k] = fmaxf(bit2 ? m[k+2] : m[k], recv);
        }
        int bit3 = (lane >> 3) & 1;
        {
            float send = bit3 ? m[0] : m[1];
            float recv = dppmov<DPP_XOR8>(send);
            m[0] = fmaxf(bit3 ? m[1] : m[0], recv);
        }
        // merge the two 16-lane groups of this batch half
        float v = m[0];
        v = fmaxf(v, __shfl_xor(v, 16, 64));
        m[0] = v;
    }

    if (alive && (lane & 16) == 0) {
        // link index = bit-reversal of lane's low 4 bits
        int k = ((lane & 1) << 3) | ((lane & 2) << 1) | ((lane & 4) >> 1) | ((lane & 8) >> 3);
        out[(size_t)b * 16 + k] = m[0];
    }
}

// ---------------------------------------------------------------------------
extern "C" void kernel_launch(void* const* d_in, const int* in_sizes, int n_in,
                              void* d_out, int out_size, void* d_ws, size_t ws_size,
                              hipStream_t stream) {
    const float* q      = (const float*)d_in[0];
    const float* frot   = (const float*)d_in[1];
    const float* ftrans = (const float*)d_in[2];
    const float* axes   = (const float*)d_in[3];
    const float* sphere = (const float*)d_in[4];
    float* out = (float*)d_out;

    const int B = in_sizes[0] / 16;
    const int blocks = (B + 7) / 8;     // 2 batches per wave, 8 per block
    fused_kernel<<<dim3(blocks), dim3(256), 0, stream>>>(
        q, frot, ftrans, axes, sphere, out, B);
}

// Round 11
// 19.780 us; speedup vs baseline: 2.7471x; 1.0110x over previous
//
#include <hip/hip_runtime.h>

typedef float v2f __attribute__((ext_vector_type(2)));

// compile-time DPP move: dest lane gets src lane per CTRL pattern.
// bound_ctrl=true: lanes whose source falls outside the 16-lane row read 0.
// NOTE: execute with source lanes ACTIVE (EXEC-disabled sources read 0).
template<int CTRL>
__device__ __forceinline__ float dppmov(float x) {
    return __builtin_bit_cast(float,
        __builtin_amdgcn_update_dpp(0, __builtin_bit_cast(int, x),
                                    CTRL, 0xf, 0xf, true));
}
#define DPP_XOR1  0xB1   // quad_perm [1,0,3,2]
#define DPP_XOR2  0x4E   // quad_perm [2,3,0,1]
#define DPP_XOR8  0x128  // row_ror:8 == lane^8 within 16-lane rows
#define DPP_SHR(d) (0x110 | (d))

// packed penetration: one row sphere vs packed column spheres {sc2, sc2+4}
// of the SAME link j -> both maxes fold with v_max3.
__device__ __forceinline__ void pen2p(const float4& rs,
                                      v2f cx, v2f cy, v2f cz, v2f cw,
                                      float& mi, float& mj)
{
    v2f dx = cx - rs.x;
    v2f dy = cy - rs.y;
    v2f dz = cz - rs.z;
    v2f d2 = dx * dx;
    d2 = __builtin_elementwise_fma(dy, dy, d2);
    d2 = __builtin_elementwise_fma(dz, dz, d2);
    v2f pen = (cw + rs.w) - (v2f){__builtin_amdgcn_sqrtf(d2.x),
                                  __builtin_amdgcn_sqrtf(d2.y)};
    mi = fmaxf(fmaxf(mi, pen.x), pen.y);   // v_max3_f32
    mj = fmaxf(fmaxf(mj, pen.x), pen.y);   // v_max3_f32
}

// ---- 3-column register tile: fill + compute, all indices compile-time ----
template<int JLO, int JHI>
__device__ __forceinline__ void fill_tile(v2f (&cx)[3], v2f (&cy)[3],
                                          v2f (&cz)[3], v2f (&cw)[3],
                                          const float* __restrict__ Sf, int sc2)
{
    #pragma unroll
    for (int j = JLO; j <= JHI; ++j) {
        const int bd = j*36 + sc2*4;
        cx[j-JLO] = (v2f){Sf[bd+0], Sf[bd+16]};
        cy[j-JLO] = (v2f){Sf[bd+1], Sf[bd+17]};
        cz[j-JLO] = (v2f){Sf[bd+2], Sf[bd+18]};
        cw[j-JLO] = (v2f){Sf[bd+3], Sf[bd+19]};
    }
}

template<int JLO, int JHI>
__device__ __forceinline__ void compute_tile(const v2f (&cx)[3], const v2f (&cy)[3],
                                             const v2f (&cz)[3], const v2f (&cw)[3],
                                             const float4* __restrict__ S,
                                             int sr, float (&m)[16])
{
    constexpr int IMAX = (JHI - 2 < 13) ? (JHI - 2) : 13;
    #pragma unroll
    for (int i = 0; i <= IMAX; ++i) {
        float4 rs = S[i*9 + sr];
        const int j0 = (i + 2 > JLO) ? (i + 2) : JLO;
        #pragma unroll
        for (int j = JLO; j <= JHI; ++j) {
            if (j < j0) continue;   // compile-time after unroll
            pen2p(rs, cx[j-JLO], cy[j-JLO], cz[j-JLO], cw[j-JLO], m[i], m[j]);
        }
    }
}

// ---------------------------------------------------------------------------
// Fully fused, TWO batches per wave (lanes 0-31 batch A, 32-63 batch B).
// 128-reg tier; <=64-reg tier unreachable (R6/R9: allocator spills all).
//  - FK prefix product via DPP row_shr, branchless (P diag forced to 1 for
//    lanes l<D; bound_ctrl zeros make those lanes compute an exact no-op).
//  - Each lane transforms 4 spheres of its link into padded LDS (stride 9).
//  - Pair phase: 32 lanes per batch; lane owns (row sr = L>>2, cols {sc2,sc2+4});
//    5 software-pipelined 3-column tiles, double-buffered (A/B) so each
//    tile's ds_reads issue under the previous tile's compute (SSA renaming
//    makes refill independent of the prior compute on the same names).
//  - Per-link max: log-fold, 13 DPP + 2 shfl + xor16 merge.
// ---------------------------------------------------------------------------
__global__ __launch_bounds__(256, 4) void fused_kernel(
    const float* __restrict__ q,        // [B,16]
    const float* __restrict__ frot,     // [16,3,3]
    const float* __restrict__ ftrans,   // [16,3]
    const float* __restrict__ axes,     // [16,3]
    const float* __restrict__ spheres,  // [16,8,4]
    float* __restrict__ out,            // [B,16]
    int B)
{
    __shared__ float4 sph[4][2][16 * 9];   // [wave][batch-half][link*9 + sphere]
    const int t    = threadIdx.x;
    const int w    = t >> 6;
    const int lane = t & 63;
    const int h    = lane >> 5;            // batch half within wave
    int b = blockIdx.x * 8 + w * 2 + h;
    const bool alive = (b < B);
    if (!alive) b = B - 1;

    const int l = lane & 15;               // link this lane owns in FK phase
    const int g = (lane >> 4) & 1;         // sphere-group (4 spheres each)

    // ---- local joint transform: R = F * J(axis,q)
    const float qv = q[(size_t)b * 16 + l];
    const float s = __sinf(qv), c = __cosf(qv), oc = 1.0f - c;
    const float ax = axes[3*l+0], ay = axes[3*l+1], az = axes[3*l+2];

    const float F00=frot[9*l+0], F01=frot[9*l+1], F02=frot[9*l+2];
    const float F10=frot[9*l+3], F11=frot[9*l+4], F12=frot[9*l+5];
    const float F20=frot[9*l+6], F21=frot[9*l+7], F22=frot[9*l+8];

    float R00,R01,R02,R10,R11,R12,R20,R21,R22;
    {
        float u0 = fmaf(F01,az, -F02*ay);
        float u1 = fmaf(F02,ax, -F00*az);
        float u2 = fmaf(F00,ay, -F01*ax);
        float v0 = fmaf(u1,az, -u2*ay);
        float v1 = fmaf(u2,ax, -u0*az);
        float v2 = fmaf(u0,ay, -u1*ax);
        R00 = fmaf(oc,v0, fmaf(s,u0, F00));
        R01 = fmaf(oc,v1, fmaf(s,u1, F01));
        R02 = fmaf(oc,v2, fmaf(s,u2, F02));

        u0 = fmaf(F11,az, -F12*ay);
        u1 = fmaf(F12,ax, -F10*az);
        u2 = fmaf(F10,ay, -F11*ax);
        v0 = fmaf(u1,az, -u2*ay);
        v1 = fmaf(u2,ax, -u0*az);
        v2 = fmaf(u0,ay, -u1*ax);
        R10 = fmaf(oc,v0, fmaf(s,u0, F10));
        R11 = fmaf(oc,v1, fmaf(s,u1, F11));
        R12 = fmaf(oc,v2, fmaf(s,u2, F12));

        u0 = fmaf(F21,az, -F22*ay);
        u1 = fmaf(F22,ax, -F20*az);
        u2 = fmaf(F20,ay, -F21*ax);
        v0 = fmaf(u1,az, -u2*ay);
        v1 = fmaf(u2,ax, -u0*az);
        v2 = fmaf(u0,ay, -u1*ax);
        R20 = fmaf(oc,v0, fmaf(s,u0, F20));
        R21 = fmaf(oc,v1, fmaf(s,u1, F21));
        R22 = fmaf(oc,v2, fmaf(s,u2, F22));
    }
    float t0 = ftrans[3*l+0], t1 = ftrans[3*l+1], t2 = ftrans[3*l+2];

    // ---- branchless Kogge-Stone prefix product over width-16 segments
    #define SCAN_STEP(D, CTRL)                                                  \
    {                                                                           \
        float P00 = dppmov<CTRL>(R00), P01 = dppmov<CTRL>(R01), P02 = dppmov<CTRL>(R02); \
        float P10 = dppmov<CTRL>(R10), P11 = dppmov<CTRL>(R11), P12 = dppmov<CTRL>(R12); \
        float P20 = dppmov<CTRL>(R20), P21 = dppmov<CTRL>(R21), P22 = dppmov<CTRL>(R22); \
        float pt0 = dppmov<CTRL>(t0),  pt1 = dppmov<CTRL>(t1),  pt2 = dppmov<CTRL>(t2);  \
        const bool lo = (l < (D));      /* P,pt are 0 here (bound_ctrl) */      \
        P00 = lo ? 1.0f : P00;                                                  \
        P11 = lo ? 1.0f : P11;                                                  \
        P22 = lo ? 1.0f : P22;          /* P = I for lo lanes -> exact no-op */ \
        {                                                                       \
            float n00 = fmaf(P00,R00, fmaf(P01,R10, P02*R20));                  \
            float n01 = fmaf(P00,R01, fmaf(P01,R11, P02*R21));                  \
            float n02 = fmaf(P00,R02, fmaf(P01,R12, P02*R22));                  \
            float n10 = fmaf(P10,R00, fmaf(P11,R10, P12*R20));                  \
            float n11 = fmaf(P10,R01, fmaf(P11,R11, P12*R21));                  \
            float n12 = fmaf(P10,R02, fmaf(P11,R12, P12*R22));                  \
            float n20 = fmaf(P20,R00, fmaf(P21,R10, P22*R20));                  \
            float n21 = fmaf(P20,R01, fmaf(P21,R11, P22*R21));                  \
            float n22 = fmaf(P20,R02, fmaf(P21,R12, P22*R22));                  \
            float nt0 = fmaf(P00,t0, fmaf(P01,t1, fmaf(P02,t2, pt0)));          \
            float nt1 = fmaf(P10,t0, fmaf(P11,t1, fmaf(P12,t2, pt1)));          \
            float nt2 = fmaf(P20,t0, fmaf(P21,t1, fmaf(P22,t2, pt2)));          \
            R00=n00; R01=n01; R02=n02;                                          \
            R10=n10; R11=n11; R12=n12;                                          \
            R20=n20; R21=n21; R22=n22;                                          \
            t0=nt0; t1=nt1; t2=nt2;                                             \
        }                                                                       \
    }
    SCAN_STEP(1, DPP_SHR(1))
    SCAN_STEP(2, DPP_SHR(2))
    SCAN_STEP(4, DPP_SHR(4))
    SCAN_STEP(8, DPP_SHR(8))
    #undef SCAN_STEP

    // ---- transform this lane's 4 spheres of link l into padded LDS
    #pragma unroll
    for (int k = 0; k < 4; ++k) {
        const int sp = g * 4 + k;
        float4 cs = reinterpret_cast<const float4*>(spheres)[l*8 + sp];
        float wx = fmaf(R00,cs.x, fmaf(R01,cs.y, fmaf(R02,cs.z, t0)));
        float wy = fmaf(R10,cs.x, fmaf(R11,cs.y, fmaf(R12,cs.z, t1)));
        float wz = fmaf(R20,cs.x, fmaf(R21,cs.y, fmaf(R22,cs.z, t2)));
        sph[w][h][l*9 + sp] = make_float4(wx, wy, wz, cs.w);
    }
    // wave-private LDS region: just drain this wave's writes, no barrier
    asm volatile("s_waitcnt lgkmcnt(0)" ::: "memory");

    // ---- pairwise penetration, per-link max (32 lanes per batch)
    const float4* S  = sph[w][h];
    const float*  Sf = reinterpret_cast<const float*>(S);
    const int L   = lane & 31;
    const int sr  = L >> 2;        // row sphere 0..7
    const int sc2 = L & 3;         // column spheres {sc2, sc2+4}

    float m[16];
    #pragma unroll
    for (int k = 0; k < 16; ++k) m[k] = -100.0f;

    // ---- 5 software-pipelined 3-column tiles, double-buffered A/B.
    // Fill of tile p+1 is issued before compute of tile p consumes its buffer;
    // SSA renaming makes the refill independent -> ds latency hides under VALU.
    {
        v2f Acx[3], Acy[3], Acz[3], Acw[3];
        v2f Bcx[3], Bcy[3], Bcz[3], Bcw[3];

        fill_tile<2,4>  (Acx,Acy,Acz,Acw, Sf, sc2);
        fill_tile<5,7>  (Bcx,Bcy,Bcz,Bcw, Sf, sc2);
        compute_tile<2,4>  (Acx,Acy,Acz,Acw, S, sr, m);
        fill_tile<8,10> (Acx,Acy,Acz,Acw, Sf, sc2);
        compute_tile<5,7>  (Bcx,Bcy,Bcz,Bcw, S, sr, m);
        fill_tile<11,13>(Bcx,Bcy,Bcz,Bcw, Sf, sc2);
        compute_tile<8,10> (Acx,Acy,Acz,Acw, S, sr, m);
        fill_tile<14,15>(Acx,Acy,Acz,Acw, Sf, sc2);
        compute_tile<11,13>(Bcx,Bcy,Bcz,Bcw, S, sr, m);
        compute_tile<14,15>(Acx,Acy,Acz,Acw, S, sr, m);
    }

    // ---- log-fold reduction over the 32 lanes of this batch half
    {
        int bit0 = lane & 1;
        #pragma unroll
        for (int k = 0; k < 8; ++k) {
            float send = bit0 ? m[k] : m[k+8];
            float recv = dppmov<DPP_XOR1>(send);
            m[k] = fmaxf(bit0 ? m[k+8] : m[k], recv);
        }
        int bit1 = (lane >> 1) & 1;
        #pragma unroll
        for (int k = 0; k < 4; ++k) {
            float send = bit1 ? m[k] : m[k+4];
            float recv = dppmov<DPP_XOR2>(send);
            m[k] = fmaxf(bit1 ? m[k+4] : m[k], recv);
        }
        int bit2 = (lane >> 2) & 1;
        #pragma unroll
        for (int k = 0; k < 2; ++k) {
            float send = bit2 ? m[k] : m[k+2];
            float recv = __shfl_xor(send, 4, 64);
            m[k] = fmaxf(bit2 ? m[k+2] : m[k], recv);
        }
        int bit3 = (lane >> 3) & 1;
        {
            float send = bit3 ? m[0] : m[1];
            float recv = dppmov<DPP_XOR8>(send);
            m[0] = fmaxf(bit3 ? m[1] : m[0], recv);
        }
        // merge the two 16-lane groups of this batch half
        float v = m[0];
        v = fmaxf(v, __shfl_xor(v, 16, 64));
        m[0] = v;
    }

    if (alive && (lane & 16) == 0) {
        // link index = bit-reversal of lane's low 4 bits
        int k = ((lane & 1) << 3) | ((lane & 2) << 1) | ((lane & 4) >> 1) | ((lane & 8) >> 3);
        out[(size_t)b * 16 + k] = m[0];
    }
}

// ---------------------------------------------------------------------------
extern "C" void kernel_launch(void* const* d_in, const int* in_sizes, int n_in,
                              void* d_out, int out_size, void* d_ws, size_t ws_size,
                              hipStream_t stream) {
    const float* q      = (const float*)d_in[0];
    const float* frot   = (const float*)d_in[1];
    const float* ftrans = (const float*)d_in[2];
    const float* axes   = (const float*)d_in[3];
    const float* sphere = (const float*)d_in[4];
    float* out = (float*)d_out;

    const int B = in_sizes[0] / 16;
    const int blocks = (B + 7) / 8;     // 2 batches per wave, 8 per block
    fused_kernel<<<dim3(blocks), dim3(256), 0, stream>>>(
        q, frot, ftrans, axes, sphere, out, B);
}